// Round 1
// 1618.839 us; speedup vs baseline: 1.0289x; 1.0289x over previous
//
#include <hip/hip_runtime.h>
#include <cstdint>
#include <cstddef>

// ---------------------------------------------------------------------------
// EncoderBlock: pre-norm MHA + pre-norm MLP, B=4 S=2048 D=2048 H=16 HD=128 DFF=8192
// GEMMs (R3): 256x256 tile, BK=32, 8 waves (2Mx4N), 3-stage circular LDS
// pipeline with COUNTED s_waitcnt vmcnt(4) at tile boundaries (never 0 in the
// main loop), raw s_barrier phases + s_setprio around MFMA clusters (T3/T4/T5).
// Swizzle folded into global source addr (T2), LDS dests stay lane-linear.
// Attention (R2): FA2-style block = 4 waves, unchanged this round.
// ---------------------------------------------------------------------------

typedef __attribute__((ext_vector_type(8))) __bf16 bf16x8;
typedef __attribute__((ext_vector_type(4))) float f32x4;

#define MFMA16(a, b, c) __builtin_amdgcn_mfma_f32_16x16x32_bf16((a), (b), (c), 0, 0, 0)

__device__ __forceinline__ unsigned short f2bf(float f) {
    unsigned int u = __builtin_bit_cast(unsigned int, f);
    u = (u + 0x7FFFu + ((u >> 16) & 1u)) >> 16;   // RNE
    return (unsigned short)u;
}

__device__ __forceinline__ void async16(const void* gptr, void* lptr) {
    __builtin_amdgcn_global_load_lds(
        (const __attribute__((address_space(1))) void*)gptr,
        (__attribute__((address_space(3))) void*)lptr, 16, 0, 0);
}

// ---------------------------------------------------------------------------
// Weight transpose + fp32->bf16 cast:  W[K][N] fp32  ->  WT[N][K] bf16
// ---------------------------------------------------------------------------
__global__ void transpose_f32_bf16(const float* __restrict__ W,
                                   unsigned short* __restrict__ WT, int K, int N) {
    __shared__ float t[32][33];
    const int n0 = blockIdx.x * 32, k0 = blockIdx.y * 32;
    const int tx = threadIdx.x, ty = threadIdx.y;
#pragma unroll
    for (int i = 0; i < 4; ++i)
        t[ty + i * 8][tx] = W[(size_t)(k0 + ty + i * 8) * N + n0 + tx];
    __syncthreads();
#pragma unroll
    for (int i = 0; i < 4; ++i)
        WT[(size_t)(n0 + ty + i * 8) * K + k0 + tx] = f2bf(t[tx][ty + i * 8]);
}

// per-(b,h) bf16 transpose: V [BH][2048][128] -> VT [BH][128][2048]
__global__ void transpose_v_bh(const unsigned short* __restrict__ V,
                               unsigned short* __restrict__ VT) {
    __shared__ unsigned short t[32][33];
    const int bh = blockIdx.z;
    const unsigned short* src = V + (size_t)bh * 2048 * 128;
    unsigned short* dst = VT + (size_t)bh * 128 * 2048;
    const int n0 = blockIdx.x * 32;   // hd
    const int k0 = blockIdx.y * 32;   // s
    const int tx = threadIdx.x, ty = threadIdx.y;
#pragma unroll
    for (int i = 0; i < 4; ++i)
        t[ty + i * 8][tx] = src[(size_t)(k0 + ty + i * 8) * 128 + n0 + tx];
    __syncthreads();
#pragma unroll
    for (int i = 0; i < 4; ++i)
        dst[(size_t)(n0 + ty + i * 8) * 2048 + k0 + tx] = t[tx][ty + i * 8];
}

// ---------------------------------------------------------------------------
// LayerNorm over D=2048, one 256-thread block per row, fp32 in -> bf16 out
// ---------------------------------------------------------------------------
__global__ void __launch_bounds__(256)
ln_kernel(const float* __restrict__ x, const float* __restrict__ w,
          const float* __restrict__ b, unsigned short* __restrict__ out) {
    const int row = blockIdx.x;
    const int tid = threadIdx.x;
    const float* xr = x + (size_t)row * 2048;
    float4 v0 = *reinterpret_cast<const float4*>(xr + tid * 8);
    float4 v1 = *reinterpret_cast<const float4*>(xr + tid * 8 + 4);
    float vv[8] = {v0.x, v0.y, v0.z, v0.w, v1.x, v1.y, v1.z, v1.w};
    float s = 0.f, q = 0.f;
#pragma unroll
    for (int j = 0; j < 8; ++j) { s += vv[j]; q += vv[j] * vv[j]; }
#pragma unroll
    for (int off = 32; off >= 1; off >>= 1) {
        s += __shfl_down(s, off);
        q += __shfl_down(q, off);
    }
    __shared__ float red[8];
    const int lane = tid & 63, wv = tid >> 6;
    if (lane == 0) { red[wv] = s; red[4 + wv] = q; }
    __syncthreads();
    s = red[0] + red[1] + red[2] + red[3];
    q = red[4] + red[5] + red[6] + red[7];
    const float mu = s * (1.f / 2048.f);
    const float var = q * (1.f / 2048.f) - mu * mu;
    const float rstd = rsqrtf(var + 1e-5f);
    alignas(16) unsigned short pk[8];
    const float* wp = w + tid * 8;
    const float* bp = b + tid * 8;
#pragma unroll
    for (int j = 0; j < 8; ++j)
        pk[j] = f2bf((vv[j] - mu) * rstd * wp[j] + bp[j]);
    *reinterpret_cast<uint4*>(out + (size_t)row * 2048 + tid * 8) =
        *reinterpret_cast<const uint4*>(pk);
}

// ---------------------------------------------------------------------------
// GEMM: C[M,N] = A[M,K] @ BT[N,K]^T   (A,BT bf16 row-major)
// 256x256 tile, BK=32, 512 threads = 8 waves (2 wave-rows x 4 wave-cols),
// per-wave 128x64 output (acc[8][4] of 16x16 frags), 16x16x32 MFMA.
// 3-stage circular LDS buffers: compute tile t from buf[t%3] while tile t+2's
// loads stream into buf[(t+2)%3] (dead since t-1). Boundary sync is a COUNTED
// s_waitcnt vmcnt(4) (one full tile stays in flight) + raw s_barrier.
// Per tile: 2 phases of {8/4 ds_read_b128 ; 2 global_load_lds ; barrier ;
// setprio(1) ; 16 MFMA ; setprio(0) ; barrier}.
// LDS swizzle: row r slot s holds global k-chunk (s - (r>>1)) & 3 (folded into
// the global source address; LDS dest stays lane-linear) -> max 2-way bank
// aliasing on ds_read_b128 (free per m136).
// Epilogues: 0 = bf16 head-layout [B,H,S,HD] with scale (QKV)
//            1 = fp32 resid + acc                         (O-proj)
//            2 = bf16 gelu_new(acc + bias)                (FC1)
//            3 = fp32 acc + bias + resid (in-place ok)    (FC2)
// ---------------------------------------------------------------------------
template <int EPI>
__global__ void __launch_bounds__(512, 2)
gemm256(const unsigned short* __restrict__ A, const unsigned short* __restrict__ BT,
        int M, int N, int K,
        const float* __restrict__ bias, const float* __restrict__ resid,
        float* __restrict__ outF, unsigned short* __restrict__ outB, float scale) {
    __shared__ __align__(16) unsigned short lds[6 * 8192];  // 96 KiB: A x3, B x3
    unsigned short* const sA = lds;
    unsigned short* const sB = lds + 3 * 8192;
    const int tid = threadIdx.x;
    const int lane = tid & 63;
    const int w = tid >> 6;
    const int wr = w >> 2;     // 0..1  (wave row: 128 C-rows each)
    const int wc = w & 3;      // 0..3  (wave col: 64 C-cols each)
    const int g = lane >> 4, lr = lane & 15;
    const int m0 = blockIdx.y * 256, n0 = blockIdx.x * 256;

    // cooperative staging map: thread stages rows r0 and r0+128 at slot tid&3;
    // slot s of row r holds global k-chunk (s - (r>>1)) & 3  (chunk = 8 bf16).
    // (r0+128)>>1 differs by 64 (== 0 mod 4) so the source chunk is shared.
    const int r0 = tid >> 2;
    const int c0 = (((tid & 3) - (r0 >> 1)) & 3) * 8;
    const unsigned short* gA0 = A + (size_t)(m0 + r0) * K + c0;
    const unsigned short* gA1 = A + (size_t)(m0 + r0 + 128) * K + c0;
    const unsigned short* gB0 = BT + (size_t)(n0 + r0) * K + c0;
    const unsigned short* gB1 = BT + (size_t)(n0 + r0 + 128) * K + c0;

    // read slot: frag k-chunk g at row R lives at slot (g + (R>>1)) & 3;
    // all frag row-bases are 0 mod 4 after >>1, so only lr contributes.
    const int sslot = ((g + ((lr >> 1) & 3)) & 3) * 8;   // in ushorts

    f32x4 acc[8][4];
#pragma unroll
    for (int i = 0; i < 8; ++i)
#pragma unroll
        for (int j = 0; j < 4; ++j)
            acc[i][j] = (f32x4){0.f, 0.f, 0.f, 0.f};

    const int NT = K >> 5;

    // prologue: tile0 -> buf0 (oldest 4 loads), tile1 -> buf1
    async16(gA0, &sA[tid * 8]);
    async16(gA1, &sA[(tid + 512) * 8]);
    async16(gB0, &sB[tid * 8]);
    async16(gB1, &sB[(tid + 512) * 8]);
    async16(gA0 + 32, &sA[8192 + tid * 8]);
    async16(gA1 + 32, &sA[8192 + (tid + 512) * 8]);
    async16(gB0 + 32, &sB[8192 + tid * 8]);
    async16(gB1 + 32, &sB[8192 + (tid + 512) * 8]);
    asm volatile("s_waitcnt vmcnt(4)" ::: "memory");   // tile0 landed
    __builtin_amdgcn_s_barrier();
    asm volatile("" ::: "memory");

    int bc = 0;
    for (int t = 0; t < NT; ++t) {
        const unsigned short* aC = sA + bc * 8192;
        const unsigned short* bC = sB + bc * 8192;
        int bs = bc + 2; if (bs >= 3) bs -= 3;
        unsigned short* aS = sA + bs * 8192;
        unsigned short* bS = sB + bs * 8192;
        const bool pf = (t + 2 < NT);
        const int kpf = (t + 2) * 32;

        bf16x8 af[4], bfr[4];
        // ---- phase 0: mb 0..3 x nb 0..3 ----
#pragma unroll
        for (int i = 0; i < 4; ++i)
            af[i] = *reinterpret_cast<const bf16x8*>(
                &aC[(wr * 128 + i * 16 + lr) * 32 + sslot]);
#pragma unroll
        for (int nf = 0; nf < 4; ++nf)
            bfr[nf] = *reinterpret_cast<const bf16x8*>(
                &bC[(wc * 64 + nf * 16 + lr) * 32 + sslot]);
        if (pf) {
            async16(gA0 + kpf, &aS[tid * 8]);
            async16(gA1 + kpf, &aS[(tid + 512) * 8]);
        }
        asm volatile("" ::: "memory");
        __builtin_amdgcn_s_barrier();
        asm volatile("" ::: "memory");
        __builtin_amdgcn_s_setprio(1);
#pragma unroll
        for (int mb = 0; mb < 4; ++mb)
#pragma unroll
            for (int nb = 0; nb < 4; ++nb)
                acc[mb][nb] = MFMA16(af[mb], bfr[nb], acc[mb][nb]);
        __builtin_amdgcn_s_setprio(0);
        asm volatile("" ::: "memory");
        __builtin_amdgcn_s_barrier();
        asm volatile("" ::: "memory");
        // ---- phase 1: mb 4..7 x nb 0..3 (bfr reused) ----
#pragma unroll
        for (int i = 0; i < 4; ++i)
            af[i] = *reinterpret_cast<const bf16x8*>(
                &aC[(wr * 128 + 64 + i * 16 + lr) * 32 + sslot]);
        if (pf) {
            async16(gB0 + kpf, &bS[tid * 8]);
            async16(gB1 + kpf, &bS[(tid + 512) * 8]);
        }
        asm volatile("" ::: "memory");
        __builtin_amdgcn_s_barrier();
        asm volatile("" ::: "memory");
        __builtin_amdgcn_s_setprio(1);
#pragma unroll
        for (int mb = 0; mb < 4; ++mb)
#pragma unroll
            for (int nb = 0; nb < 4; ++nb)
                acc[4 + mb][nb] = MFMA16(af[mb], bfr[nb], acc[4 + mb][nb]);
        __builtin_amdgcn_s_setprio(0);
        if (t < NT - 1) {
            // counted drain: tile t+1's 4 loads retire, tile t+2's 4 stay in flight
            if (pf) asm volatile("s_waitcnt vmcnt(4)" ::: "memory");
            else    asm volatile("s_waitcnt vmcnt(0)" ::: "memory");
        }
        asm volatile("" ::: "memory");
        __builtin_amdgcn_s_barrier();
        asm volatile("" ::: "memory");
        bc = (bc + 1 == 3) ? 0 : bc + 1;
    }

    // epilogue: C row = m0 + wr*128 + mb*16 + g*4 + r, col = n0 + wc*64 + nb*16 + lr
#pragma unroll
    for (int mb = 0; mb < 8; ++mb) {
#pragma unroll
        for (int r = 0; r < 4; ++r) {
            const int m = m0 + wr * 128 + mb * 16 + g * 4 + r;
#pragma unroll
            for (int nb = 0; nb < 4; ++nb) {
                const int n = n0 + wc * 64 + nb * 16 + lr;
                float v = acc[mb][nb][r];
                if constexpr (EPI == 0) {
                    v *= scale;
                    const int b = m >> 11, s = m & 2047;
                    const int h = n >> 7, hd = n & 127;
                    outB[(((size_t)(b * 16 + h) * 2048 + s) << 7) + hd] = f2bf(v);
                } else if constexpr (EPI == 1) {
                    const size_t idx = (size_t)m * N + n;
                    outF[idx] = resid[idx] + v;
                } else if constexpr (EPI == 2) {
                    v += bias[n];
                    const float u = 0.7978845608028654f * (v + 0.044715f * v * v * v);
                    const float ge = 0.5f * v * (1.f + tanhf(u));
                    outB[(size_t)m * N + n] = f2bf(ge);
                } else {
                    const size_t idx = (size_t)m * N + n;
                    outF[idx] = v + bias[n] + resid[idx];
                }
            }
        }
    }
}

// ---------------------------------------------------------------------------
// Flash attention (FA2-style): 256 threads = 4 waves per block. (unchanged R2)
// ---------------------------------------------------------------------------
__global__ void __launch_bounds__(256)
attn_kernel(const unsigned short* __restrict__ Q, const unsigned short* __restrict__ Kt,
            const unsigned short* __restrict__ VT, unsigned short* __restrict__ O) {
    __shared__ __align__(16) unsigned short lK[64 * 128];   // 16 KB [key][hd]
    __shared__ __align__(16) unsigned short lV[128 * 64];   // 16 KB [hd][key]
    __shared__ __align__(16) unsigned short lP[4][16 * 64]; //  8 KB per-wave P
    const int bh = blockIdx.y;
    const int qt = blockIdx.x;
    const int tid = threadIdx.x;
    const int w = tid >> 6;
    const int lane = tid & 63;
    const int g = lane >> 4, lr = lane & 15;
    const unsigned short* Qp = Q + ((size_t)bh * 2048 + qt * 64 + w * 16) * 128;
    const unsigned short* Kp = Kt + (size_t)bh * 2048 * 128;
    const unsigned short* Vp = VT + (size_t)bh * 128 * 2048;
    unsigned short* Pw = lP[w];

    bf16x8 qf[4];
#pragma unroll
    for (int c = 0; c < 4; ++c)
        qf[c] = *reinterpret_cast<const bf16x8*>(&Qp[lr * 128 + c * 32 + g * 8]);

    f32x4 o[8];
#pragma unroll
    for (int db = 0; db < 8; ++db) o[db] = (f32x4){0.f, 0.f, 0.f, 0.f};
    float mm[4] = {-1e30f, -1e30f, -1e30f, -1e30f};
    float ll[4] = {0.f, 0.f, 0.f, 0.f};

    int kR[4], kJ[4], vR[4], vJ[4];
#pragma unroll
    for (int c = 0; c < 4; ++c) {
        const int chunk = tid + c * 256;
        kR[c] = chunk >> 4;
        kJ[c] = ((chunk & 15) ^ (kR[c] & 15)) * 8;
        vR[c] = chunk >> 3;
        vJ[c] = ((chunk & 7) ^ (vR[c] & 7)) * 8;
    }

    for (int kt = 0; kt < 32; ++kt) {
        const int kb = kt * 64;
        __syncthreads();
#pragma unroll
        for (int c = 0; c < 4; ++c) {
            async16(&Kp[(size_t)(kb + kR[c]) * 128 + kJ[c]], &lK[(size_t)(tid + c * 256) * 8]);
            async16(&Vp[(size_t)vR[c] * 2048 + kb + vJ[c]], &lV[(size_t)(tid + c * 256) * 8]);
        }
        __syncthreads();

        f32x4 sc[4];
#pragma unroll
        for (int j16 = 0; j16 < 4; ++j16) sc[j16] = (f32x4){0.f, 0.f, 0.f, 0.f};
#pragma unroll
        for (int j16 = 0; j16 < 4; ++j16) {
            const int krow = j16 * 16 + lr;
#pragma unroll
            for (int c = 0; c < 4; ++c) {
                bf16x8 kf = *reinterpret_cast<const bf16x8*>(
                    &lK[krow * 128 + (((c * 4 + g) ^ lr) & 15) * 8]);
                sc[j16] = MFMA16(qf[c], kf, sc[j16]);
            }
        }

        float al[4];
        float pr[4][4];
#pragma unroll
        for (int r = 0; r < 4; ++r) {
            float mx = fmaxf(fmaxf(sc[0][r], sc[1][r]), fmaxf(sc[2][r], sc[3][r]));
            mx = fmaxf(mx, __shfl_xor(mx, 1));
            mx = fmaxf(mx, __shfl_xor(mx, 2));
            mx = fmaxf(mx, __shfl_xor(mx, 4));
            mx = fmaxf(mx, __shfl_xor(mx, 8));
            const float nm = fmaxf(mm[r], mx);
            al[r] = __expf(mm[r] - nm);
            float rs = 0.f;
#pragma unroll
            for (int j16 = 0; j16 < 4; ++j16) {
                pr[j16][r] = __expf(sc[j16][r] - nm);
                rs += pr[j16][r];
            }
            rs += __shfl_xor(rs, 1);
            rs += __shfl_xor(rs, 2);
            rs += __shfl_xor(rs, 4);
            rs += __shfl_xor(rs, 8);
            ll[r] = ll[r] * al[r] + rs;
            mm[r] = nm;
        }
#pragma unroll
        for (int db = 0; db < 8; ++db) {
            o[db][0] *= al[0]; o[db][1] *= al[1];
            o[db][2] *= al[2]; o[db][3] *= al[3];
        }

#pragma unroll
        for (int j16 = 0; j16 < 4; ++j16)
#pragma unroll
            for (int r = 0; r < 4; ++r) {
                const int row = g * 4 + r;
                const int ch = j16 * 2 + (lr >> 3);
                Pw[row * 64 + ((ch ^ (row & 7)) * 8) + (lr & 7)] = f2bf(pr[j16][r]);
            }

#pragma unroll
        for (int kk = 0; kk < 2; ++kk) {
            bf16x8 pf = *reinterpret_cast<const bf16x8*>(
                &Pw[lr * 64 + (((kk * 4 + g) ^ (lr & 7)) & 7) * 8]);
#pragma unroll
            for (int db = 0; db < 8; ++db) {
                const int vrow = db * 16 + lr;
                bf16x8 vf = *reinterpret_cast<const bf16x8*>(
                    &lV[vrow * 64 + (((kk * 4 + g) ^ (vrow & 7)) & 7) * 8]);
                o[db] = MFMA16(pf, vf, o[db]);
            }
        }
    }

    const int b = bh >> 4, h = bh & 15;
#pragma unroll
    for (int db = 0; db < 8; ++db)
#pragma unroll
        for (int r = 0; r < 4; ++r) {
            const int s = qt * 64 + w * 16 + g * 4 + r;
            const float v = o[db][r] / ll[r];
            O[((size_t)(b * 2048 + s)) * 2048 + h * 128 + db * 16 + lr] = f2bf(v);
        }
}

// ---------------------------------------------------------------------------
extern "C" void kernel_launch(void* const* d_in, const int* in_sizes, int n_in,
                              void* d_out, int out_size, void* d_ws, size_t ws_size,
                              hipStream_t stream) {
    const float* x    = (const float*)d_in[0];
    const float* wq   = (const float*)d_in[1];
    const float* wk   = (const float*)d_in[2];
    const float* wv   = (const float*)d_in[3];
    const float* wo   = (const float*)d_in[4];
    const float* ln1w = (const float*)d_in[5];
    const float* ln1b = (const float*)d_in[6];
    const float* ln2w = (const float*)d_in[7];
    const float* ln2b = (const float*)d_in[8];
    const float* fc1w = (const float*)d_in[9];
    const float* fc1b = (const float*)d_in[10];
    const float* fc2w = (const float*)d_in[11];
    const float* fc2b = (const float*)d_in[12];
    float* out = (float*)d_out;

    const size_t MB = 1024ull * 1024ull;
    if (ws_size < 200 * MB) return;  // diagnostic guard

    char* ws = (char*)d_ws;
    unsigned short* W8   = (unsigned short*)(ws + 0 * MB);    //  8 MB: wqT/wkT/wvT/woT (seq.)
    unsigned short* W32  = (unsigned short*)(ws + 8 * MB);    // 32 MB: fc1T then fc2T
    unsigned short* act  = (unsigned short*)(ws + 40 * MB);   // 32 MB: h -> attnO -> h2
    unsigned short* qb   = (unsigned short*)(ws + 72 * MB);   // 32 MB
    unsigned short* kb   = (unsigned short*)(ws + 104 * MB);  // 32 MB
    unsigned short* vb   = (unsigned short*)(ws + 136 * MB);  // 32 MB
    unsigned short* vtb  = (unsigned short*)(ws + 168 * MB);  // 32 MB
    unsigned short* mid  = qb;                                // 128 MB overlay (post-attn)
    float*          x1   = out;                               // x + attn proj in d_out

    const dim3 tb(32, 8);
    const float qscale = 0.08838834764831845f;

    // LN1: x -> h (bf16)
    ln_kernel<<<8192, 256, 0, stream>>>(x, ln1w, ln1b, act);

    // Q = h @ wq (scaled), head layout
    transpose_f32_bf16<<<dim3(64, 64), tb, 0, stream>>>(wq, W8, 2048, 2048);
    gemm256<0><<<dim3(8, 32), 512, 0, stream>>>(act, W8, 8192, 2048, 2048,
                                                nullptr, nullptr, nullptr, qb, qscale);
    // K
    transpose_f32_bf16<<<dim3(64, 64), tb, 0, stream>>>(wk, W8, 2048, 2048);
    gemm256<0><<<dim3(8, 32), 512, 0, stream>>>(act, W8, 8192, 2048, 2048,
                                                nullptr, nullptr, nullptr, kb, 1.f);
    // V
    transpose_f32_bf16<<<dim3(64, 64), tb, 0, stream>>>(wv, W8, 2048, 2048);
    gemm256<0><<<dim3(8, 32), 512, 0, stream>>>(act, W8, 8192, 2048, 2048,
                                                nullptr, nullptr, nullptr, vb, 1.f);

    // V -> V^T per (b,h)
    transpose_v_bh<<<dim3(4, 64, 64), tb, 0, stream>>>(vb, vtb);

    // attention -> act ([B,S,D] bf16)
    attn_kernel<<<dim3(32, 64), 256, 0, stream>>>(qb, kb, vtb, act);

    // O-proj + residual -> x1 (= d_out, fp32)
    transpose_f32_bf16<<<dim3(64, 64), tb, 0, stream>>>(wo, W8, 2048, 2048);
    gemm256<1><<<dim3(8, 32), 512, 0, stream>>>(act, W8, 8192, 2048, 2048,
                                                nullptr, x, x1, nullptr, 1.f);

    // LN2: x1 -> h2 (bf16, into act)
    ln_kernel<<<8192, 256, 0, stream>>>(x1, ln2w, ln2b, act);

    // FC1 + bias + gelu_new -> mid (bf16)
    transpose_f32_bf16<<<dim3(256, 64), tb, 0, stream>>>(fc1w, W32, 2048, 8192);
    gemm256<2><<<dim3(32, 32), 512, 0, stream>>>(act, W32, 8192, 8192, 2048,
                                                 fc1b, nullptr, nullptr, mid, 1.f);

    // FC2 + bias + residual(x1 in d_out) -> d_out (in-place RMW, one touch/elem)
    transpose_f32_bf16<<<dim3(64, 256), tb, 0, stream>>>(fc2w, W32, 8192, 2048);
    gemm256<3><<<dim3(8, 32), 512, 0, stream>>>(mid, W32, 8192, 2048, 8192,
                                                fc2b, x1, out, nullptr, 1.f);
}

// Round 2
// 1544.572 us; speedup vs baseline: 1.0784x; 1.0481x over previous
//
#include <hip/hip_runtime.h>
#include <cstdint>
#include <cstddef>

// ---------------------------------------------------------------------------
// EncoderBlock: pre-norm MHA + pre-norm MLP, B=4 S=2048 D=2048 H=16 HD=128 DFF=8192
// GEMMs (R4): 256x256 tile, BK=32, 8 waves (2Mx4N), 3-stage circular LDS
// pipeline, COUNTED s_waitcnt vmcnt(4) at tile boundaries.
// R4 fix vs R3: NO "memory" clobbers on the waitcnt asm and NO bare
// asm-memory fences -- those made LLVM's waitcnt pass insert a full
// s_waitcnt vmcnt(0) lgkmcnt(0) before every fence (defensive drain before
// opaque asm), serializing HBM latency into every phase (~4000 cyc/K-tile).
// Ordering is pinned with __builtin_amdgcn_sched_barrier(0) instead
// (compile-time fence, emits nothing, triggers no waitcnt). This is the
// verified m201/HK pattern (guide rule 18 + T3/T4 recipe).
// Attention (R2): FA2-style block = 4 waves, unchanged this round.
// ---------------------------------------------------------------------------

typedef __attribute__((ext_vector_type(8))) __bf16 bf16x8;
typedef __attribute__((ext_vector_type(4))) float f32x4;

#define MFMA16(a, b, c) __builtin_amdgcn_mfma_f32_16x16x32_bf16((a), (b), (c), 0, 0, 0)
#define SCHED_FENCE() __builtin_amdgcn_sched_barrier(0)

__device__ __forceinline__ unsigned short f2bf(float f) {
    unsigned int u = __builtin_bit_cast(unsigned int, f);
    u = (u + 0x7FFFu + ((u >> 16) & 1u)) >> 16;   // RNE
    return (unsigned short)u;
}

__device__ __forceinline__ void async16(const void* gptr, void* lptr) {
    __builtin_amdgcn_global_load_lds(
        (const __attribute__((address_space(1))) void*)gptr,
        (__attribute__((address_space(3))) void*)lptr, 16, 0, 0);
}

// ---------------------------------------------------------------------------
// Weight transpose + fp32->bf16 cast:  W[K][N] fp32  ->  WT[N][K] bf16
// ---------------------------------------------------------------------------
__global__ void transpose_f32_bf16(const float* __restrict__ W,
                                   unsigned short* __restrict__ WT, int K, int N) {
    __shared__ float t[32][33];
    const int n0 = blockIdx.x * 32, k0 = blockIdx.y * 32;
    const int tx = threadIdx.x, ty = threadIdx.y;
#pragma unroll
    for (int i = 0; i < 4; ++i)
        t[ty + i * 8][tx] = W[(size_t)(k0 + ty + i * 8) * N + n0 + tx];
    __syncthreads();
#pragma unroll
    for (int i = 0; i < 4; ++i)
        WT[(size_t)(n0 + ty + i * 8) * K + k0 + tx] = f2bf(t[tx][ty + i * 8]);
}

// per-(b,h) bf16 transpose: V [BH][2048][128] -> VT [BH][128][2048]
__global__ void transpose_v_bh(const unsigned short* __restrict__ V,
                               unsigned short* __restrict__ VT) {
    __shared__ unsigned short t[32][33];
    const int bh = blockIdx.z;
    const unsigned short* src = V + (size_t)bh * 2048 * 128;
    unsigned short* dst = VT + (size_t)bh * 128 * 2048;
    const int n0 = blockIdx.x * 32;   // hd
    const int k0 = blockIdx.y * 32;   // s
    const int tx = threadIdx.x, ty = threadIdx.y;
#pragma unroll
    for (int i = 0; i < 4; ++i)
        t[ty + i * 8][tx] = src[(size_t)(k0 + ty + i * 8) * 128 + n0 + tx];
    __syncthreads();
#pragma unroll
    for (int i = 0; i < 4; ++i)
        dst[(size_t)(n0 + ty + i * 8) * 2048 + k0 + tx] = t[tx][ty + i * 8];
}

// ---------------------------------------------------------------------------
// LayerNorm over D=2048, one 256-thread block per row, fp32 in -> bf16 out
// ---------------------------------------------------------------------------
__global__ void __launch_bounds__(256)
ln_kernel(const float* __restrict__ x, const float* __restrict__ w,
          const float* __restrict__ b, unsigned short* __restrict__ out) {
    const int row = blockIdx.x;
    const int tid = threadIdx.x;
    const float* xr = x + (size_t)row * 2048;
    float4 v0 = *reinterpret_cast<const float4*>(xr + tid * 8);
    float4 v1 = *reinterpret_cast<const float4*>(xr + tid * 8 + 4);
    float vv[8] = {v0.x, v0.y, v0.z, v0.w, v1.x, v1.y, v1.z, v1.w};
    float s = 0.f, q = 0.f;
#pragma unroll
    for (int j = 0; j < 8; ++j) { s += vv[j]; q += vv[j] * vv[j]; }
#pragma unroll
    for (int off = 32; off >= 1; off >>= 1) {
        s += __shfl_down(s, off);
        q += __shfl_down(q, off);
    }
    __shared__ float red[8];
    const int lane = tid & 63, wv = tid >> 6;
    if (lane == 0) { red[wv] = s; red[4 + wv] = q; }
    __syncthreads();
    s = red[0] + red[1] + red[2] + red[3];
    q = red[4] + red[5] + red[6] + red[7];
    const float mu = s * (1.f / 2048.f);
    const float var = q * (1.f / 2048.f) - mu * mu;
    const float rstd = rsqrtf(var + 1e-5f);
    alignas(16) unsigned short pk[8];
    const float* wp = w + tid * 8;
    const float* bp = b + tid * 8;
#pragma unroll
    for (int j = 0; j < 8; ++j)
        pk[j] = f2bf((vv[j] - mu) * rstd * wp[j] + bp[j]);
    *reinterpret_cast<uint4*>(out + (size_t)row * 2048 + tid * 8) =
        *reinterpret_cast<const uint4*>(pk);
}

// ---------------------------------------------------------------------------
// GEMM: C[M,N] = A[M,K] @ BT[N,K]^T   (A,BT bf16 row-major)
// 256x256 tile, BK=32, 512 threads = 8 waves (2 wave-rows x 4 wave-cols),
// per-wave 128x64 output (acc[8][4] of 16x16 frags), 16x16x32 MFMA.
// 3-stage circular LDS buffers: compute tile t from buf[t%3] while tile t+2's
// loads stream into buf[(t+2)%3] (dead since t-1). Boundary sync is a COUNTED
// s_waitcnt vmcnt(4) (one full tile stays in flight) + raw s_barrier.
// Per tile: 2 phases of {8/4 ds_read_b128 ; 2 global_load_lds ; barrier ;
// setprio(1) ; 16 MFMA ; setprio(0) ; barrier}.
// LDS swizzle: row r slot s holds global k-chunk (s - (r>>1)) & 3 (folded into
// the global source address; LDS dest stays lane-linear) -> max 2-way bank
// aliasing on ds_read_b128 (free per m136).
// Epilogues: 0 = bf16 head-layout [B,H,S,HD] with scale (QKV)
//            1 = fp32 resid + acc                         (O-proj)
//            2 = bf16 gelu_new(acc + bias)                (FC1)
//            3 = fp32 acc + bias + resid (in-place ok)    (FC2)
// ---------------------------------------------------------------------------
template <int EPI>
__global__ void __launch_bounds__(512, 2)
gemm256(const unsigned short* __restrict__ A, const unsigned short* __restrict__ BT,
        int M, int N, int K,
        const float* __restrict__ bias, const float* __restrict__ resid,
        float* __restrict__ outF, unsigned short* __restrict__ outB, float scale) {
    __shared__ __align__(16) unsigned short lds[6 * 8192];  // 96 KiB: A x3, B x3
    unsigned short* const sA = lds;
    unsigned short* const sB = lds + 3 * 8192;
    const int tid = threadIdx.x;
    const int lane = tid & 63;
    const int w = tid >> 6;
    const int wr = w >> 2;     // 0..1  (wave row: 128 C-rows each)
    const int wc = w & 3;      // 0..3  (wave col: 64 C-cols each)
    const int g = lane >> 4, lr = lane & 15;
    const int m0 = blockIdx.y * 256, n0 = blockIdx.x * 256;

    // cooperative staging map: thread stages rows r0 and r0+128 at slot tid&3;
    // slot s of row r holds global k-chunk (s - (r>>1)) & 3  (chunk = 8 bf16).
    const int r0 = tid >> 2;
    const int c0 = (((tid & 3) - (r0 >> 1)) & 3) * 8;
    const unsigned short* gA0 = A + (size_t)(m0 + r0) * K + c0;
    const unsigned short* gA1 = A + (size_t)(m0 + r0 + 128) * K + c0;
    const unsigned short* gB0 = BT + (size_t)(n0 + r0) * K + c0;
    const unsigned short* gB1 = BT + (size_t)(n0 + r0 + 128) * K + c0;

    // read slot: frag k-chunk g at row R lives at slot (g + (R>>1)) & 3;
    // all frag row-bases are 0 mod 4 after >>1, so only lr contributes.
    const int sslot = ((g + ((lr >> 1) & 3)) & 3) * 8;   // in ushorts

    f32x4 acc[8][4];
#pragma unroll
    for (int i = 0; i < 8; ++i)
#pragma unroll
        for (int j = 0; j < 4; ++j)
            acc[i][j] = (f32x4){0.f, 0.f, 0.f, 0.f};

    const int NT = K >> 5;

    // prologue: tile0 -> buf0 (oldest 4 loads), tile1 -> buf1
    async16(gA0, &sA[tid * 8]);
    async16(gA1, &sA[(tid + 512) * 8]);
    async16(gB0, &sB[tid * 8]);
    async16(gB1, &sB[(tid + 512) * 8]);
    async16(gA0 + 32, &sA[8192 + tid * 8]);
    async16(gA1 + 32, &sA[8192 + (tid + 512) * 8]);
    async16(gB0 + 32, &sB[8192 + tid * 8]);
    async16(gB1 + 32, &sB[8192 + (tid + 512) * 8]);
    asm volatile("s_waitcnt vmcnt(4)");   // tile0 landed (bare: no mem clobber!)
    SCHED_FENCE();
    __builtin_amdgcn_s_barrier();
    SCHED_FENCE();

    int bc = 0;
    for (int t = 0; t < NT; ++t) {
        const unsigned short* aC = sA + bc * 8192;
        const unsigned short* bC = sB + bc * 8192;
        int bs = bc + 2; if (bs >= 3) bs -= 3;
        unsigned short* aS = sA + bs * 8192;
        unsigned short* bS = sB + bs * 8192;
        const bool pf = (t + 2 < NT);
        const int kpf = (t + 2) * 32;

        bf16x8 af[4], bfr[4];
        // ---- phase 0: mb 0..3 x nb 0..3 ----
#pragma unroll
        for (int i = 0; i < 4; ++i)
            af[i] = *reinterpret_cast<const bf16x8*>(
                &aC[(wr * 128 + i * 16 + lr) * 32 + sslot]);
#pragma unroll
        for (int nf = 0; nf < 4; ++nf)
            bfr[nf] = *reinterpret_cast<const bf16x8*>(
                &bC[(wc * 64 + nf * 16 + lr) * 32 + sslot]);
        if (pf) {
            async16(gA0 + kpf, &aS[tid * 8]);
            async16(gA1 + kpf, &aS[(tid + 512) * 8]);
        }
        SCHED_FENCE();
        __builtin_amdgcn_s_barrier();
        SCHED_FENCE();
        __builtin_amdgcn_s_setprio(1);
#pragma unroll
        for (int mb = 0; mb < 4; ++mb)
#pragma unroll
            for (int nb = 0; nb < 4; ++nb)
                acc[mb][nb] = MFMA16(af[mb], bfr[nb], acc[mb][nb]);
        __builtin_amdgcn_s_setprio(0);
        SCHED_FENCE();
        __builtin_amdgcn_s_barrier();
        SCHED_FENCE();
        // ---- phase 1: mb 4..7 x nb 0..3 (bfr reused) ----
#pragma unroll
        for (int i = 0; i < 4; ++i)
            af[i] = *reinterpret_cast<const bf16x8*>(
                &aC[(wr * 128 + 64 + i * 16 + lr) * 32 + sslot]);
        if (pf) {
            async16(gB0 + kpf, &bS[tid * 8]);
            async16(gB1 + kpf, &bS[(tid + 512) * 8]);
        }
        SCHED_FENCE();
        __builtin_amdgcn_s_barrier();
        SCHED_FENCE();
        __builtin_amdgcn_s_setprio(1);
#pragma unroll
        for (int mb = 0; mb < 4; ++mb)
#pragma unroll
            for (int nb = 0; nb < 4; ++nb)
                acc[4 + mb][nb] = MFMA16(af[mb], bfr[nb], acc[4 + mb][nb]);
        __builtin_amdgcn_s_setprio(0);
        SCHED_FENCE();
        if (t < NT - 1) {
            // counted drain: tile t+1's 4 loads retire, tile t+2's 4 stay in flight
            if (pf) asm volatile("s_waitcnt vmcnt(4)");
            else    asm volatile("s_waitcnt vmcnt(0)");
        }
        SCHED_FENCE();
        __builtin_amdgcn_s_barrier();
        SCHED_FENCE();
        bc = (bc + 1 == 3) ? 0 : bc + 1;
    }

    // epilogue: C row = m0 + wr*128 + mb*16 + g*4 + r, col = n0 + wc*64 + nb*16 + lr
#pragma unroll
    for (int mb = 0; mb < 8; ++mb) {
#pragma unroll
        for (int r = 0; r < 4; ++r) {
            const int m = m0 + wr * 128 + mb * 16 + g * 4 + r;
#pragma unroll
            for (int nb = 0; nb < 4; ++nb) {
                const int n = n0 + wc * 64 + nb * 16 + lr;
                float v = acc[mb][nb][r];
                if constexpr (EPI == 0) {
                    v *= scale;
                    const int b = m >> 11, s = m & 2047;
                    const int h = n >> 7, hd = n & 127;
                    outB[(((size_t)(b * 16 + h) * 2048 + s) << 7) + hd] = f2bf(v);
                } else if constexpr (EPI == 1) {
                    const size_t idx = (size_t)m * N + n;
                    outF[idx] = resid[idx] + v;
                } else if constexpr (EPI == 2) {
                    v += bias[n];
                    const float u = 0.7978845608028654f * (v + 0.044715f * v * v * v);
                    const float ge = 0.5f * v * (1.f + tanhf(u));
                    outB[(size_t)m * N + n] = f2bf(ge);
                } else {
                    const size_t idx = (size_t)m * N + n;
                    outF[idx] = v + bias[n] + resid[idx];
                }
            }
        }
    }
}

// ---------------------------------------------------------------------------
// Flash attention (FA2-style): 256 threads = 4 waves per block. (unchanged)
// ---------------------------------------------------------------------------
__global__ void __launch_bounds__(256)
attn_kernel(const unsigned short* __restrict__ Q, const unsigned short* __restrict__ Kt,
            const unsigned short* __restrict__ VT, unsigned short* __restrict__ O) {
    __shared__ __align__(16) unsigned short lK[64 * 128];   // 16 KB [key][hd]
    __shared__ __align__(16) unsigned short lV[128 * 64];   // 16 KB [hd][key]
    __shared__ __align__(16) unsigned short lP[4][16 * 64]; //  8 KB per-wave P
    const int bh = blockIdx.y;
    const int qt = blockIdx.x;
    const int tid = threadIdx.x;
    const int w = tid >> 6;
    const int lane = tid & 63;
    const int g = lane >> 4, lr = lane & 15;
    const unsigned short* Qp = Q + ((size_t)bh * 2048 + qt * 64 + w * 16) * 128;
    const unsigned short* Kp = Kt + (size_t)bh * 2048 * 128;
    const unsigned short* Vp = VT + (size_t)bh * 128 * 2048;
    unsigned short* Pw = lP[w];

    bf16x8 qf[4];
#pragma unroll
    for (int c = 0; c < 4; ++c)
        qf[c] = *reinterpret_cast<const bf16x8*>(&Qp[lr * 128 + c * 32 + g * 8]);

    f32x4 o[8];
#pragma unroll
    for (int db = 0; db < 8; ++db) o[db] = (f32x4){0.f, 0.f, 0.f, 0.f};
    float mm[4] = {-1e30f, -1e30f, -1e30f, -1e30f};
    float ll[4] = {0.f, 0.f, 0.f, 0.f};

    int kR[4], kJ[4], vR[4], vJ[4];
#pragma unroll
    for (int c = 0; c < 4; ++c) {
        const int chunk = tid + c * 256;
        kR[c] = chunk >> 4;
        kJ[c] = ((chunk & 15) ^ (kR[c] & 15)) * 8;
        vR[c] = chunk >> 3;
        vJ[c] = ((chunk & 7) ^ (vR[c] & 7)) * 8;
    }

    for (int kt = 0; kt < 32; ++kt) {
        const int kb = kt * 64;
        __syncthreads();
#pragma unroll
        for (int c = 0; c < 4; ++c) {
            async16(&Kp[(size_t)(kb + kR[c]) * 128 + kJ[c]], &lK[(size_t)(tid + c * 256) * 8]);
            async16(&Vp[(size_t)vR[c] * 2048 + kb + vJ[c]], &lV[(size_t)(tid + c * 256) * 8]);
        }
        __syncthreads();

        f32x4 sc[4];
#pragma unroll
        for (int j16 = 0; j16 < 4; ++j16) sc[j16] = (f32x4){0.f, 0.f, 0.f, 0.f};
#pragma unroll
        for (int j16 = 0; j16 < 4; ++j16) {
            const int krow = j16 * 16 + lr;
#pragma unroll
            for (int c = 0; c < 4; ++c) {
                bf16x8 kf = *reinterpret_cast<const bf16x8*>(
                    &lK[krow * 128 + (((c * 4 + g) ^ lr) & 15) * 8]);
                sc[j16] = MFMA16(qf[c], kf, sc[j16]);
            }
        }

        float al[4];
        float pr[4][4];
#pragma unroll
        for (int r = 0; r < 4; ++r) {
            float mx = fmaxf(fmaxf(sc[0][r], sc[1][r]), fmaxf(sc[2][r], sc[3][r]));
            mx = fmaxf(mx, __shfl_xor(mx, 1));
            mx = fmaxf(mx, __shfl_xor(mx, 2));
            mx = fmaxf(mx, __shfl_xor(mx, 4));
            mx = fmaxf(mx, __shfl_xor(mx, 8));
            const float nm = fmaxf(mm[r], mx);
            al[r] = __expf(mm[r] - nm);
            float rs = 0.f;
#pragma unroll
            for (int j16 = 0; j16 < 4; ++j16) {
                pr[j16][r] = __expf(sc[j16][r] - nm);
                rs += pr[j16][r];
            }
            rs += __shfl_xor(rs, 1);
            rs += __shfl_xor(rs, 2);
            rs += __shfl_xor(rs, 4);
            rs += __shfl_xor(rs, 8);
            ll[r] = ll[r] * al[r] + rs;
            mm[r] = nm;
        }
#pragma unroll
        for (int db = 0; db < 8; ++db) {
            o[db][0] *= al[0]; o[db][1] *= al[1];
            o[db][2] *= al[2]; o[db][3] *= al[3];
        }

#pragma unroll
        for (int j16 = 0; j16 < 4; ++j16)
#pragma unroll
            for (int r = 0; r < 4; ++r) {
                const int row = g * 4 + r;
                const int ch = j16 * 2 + (lr >> 3);
                Pw[row * 64 + ((ch ^ (row & 7)) * 8) + (lr & 7)] = f2bf(pr[j16][r]);
            }

#pragma unroll
        for (int kk = 0; kk < 2; ++kk) {
            bf16x8 pf = *reinterpret_cast<const bf16x8*>(
                &Pw[lr * 64 + (((kk * 4 + g) ^ (lr & 7)) & 7) * 8]);
#pragma unroll
            for (int db = 0; db < 8; ++db) {
                const int vrow = db * 16 + lr;
                bf16x8 vf = *reinterpret_cast<const bf16x8*>(
                    &lV[vrow * 64 + (((kk * 4 + g) ^ (vrow & 7)) & 7) * 8]);
                o[db] = MFMA16(pf, vf, o[db]);
            }
        }
    }

    const int b = bh >> 4, h = bh & 15;
#pragma unroll
    for (int db = 0; db < 8; ++db)
#pragma unroll
        for (int r = 0; r < 4; ++r) {
            const int s = qt * 64 + w * 16 + g * 4 + r;
            const float v = o[db][r] / ll[r];
            O[((size_t)(b * 2048 + s)) * 2048 + h * 128 + db * 16 + lr] = f2bf(v);
        }
}

// ---------------------------------------------------------------------------
extern "C" void kernel_launch(void* const* d_in, const int* in_sizes, int n_in,
                              void* d_out, int out_size, void* d_ws, size_t ws_size,
                              hipStream_t stream) {
    const float* x    = (const float*)d_in[0];
    const float* wq   = (const float*)d_in[1];
    const float* wk   = (const float*)d_in[2];
    const float* wv   = (const float*)d_in[3];
    const float* wo   = (const float*)d_in[4];
    const float* ln1w = (const float*)d_in[5];
    const float* ln1b = (const float*)d_in[6];
    const float* ln2w = (const float*)d_in[7];
    const float* ln2b = (const float*)d_in[8];
    const float* fc1w = (const float*)d_in[9];
    const float* fc1b = (const float*)d_in[10];
    const float* fc2w = (const float*)d_in[11];
    const float* fc2b = (const float*)d_in[12];
    float* out = (float*)d_out;

    const size_t MB = 1024ull * 1024ull;
    if (ws_size < 200 * MB) return;  // diagnostic guard

    char* ws = (char*)d_ws;
    unsigned short* W8   = (unsigned short*)(ws + 0 * MB);    //  8 MB: wqT/wkT/wvT/woT (seq.)
    unsigned short* W32  = (unsigned short*)(ws + 8 * MB);    // 32 MB: fc1T then fc2T
    unsigned short* act  = (unsigned short*)(ws + 40 * MB);   // 32 MB: h -> attnO -> h2
    unsigned short* qb   = (unsigned short*)(ws + 72 * MB);   // 32 MB
    unsigned short* kb   = (unsigned short*)(ws + 104 * MB);  // 32 MB
    unsigned short* vb   = (unsigned short*)(ws + 136 * MB);  // 32 MB
    unsigned short* vtb  = (unsigned short*)(ws + 168 * MB);  // 32 MB
    unsigned short* mid  = qb;                                // 128 MB overlay (post-attn)
    float*          x1   = out;                               // x + attn proj in d_out

    const dim3 tb(32, 8);
    const float qscale = 0.08838834764831845f;

    // LN1: x -> h (bf16)
    ln_kernel<<<8192, 256, 0, stream>>>(x, ln1w, ln1b, act);

    // Q = h @ wq (scaled), head layout
    transpose_f32_bf16<<<dim3(64, 64), tb, 0, stream>>>(wq, W8, 2048, 2048);
    gemm256<0><<<dim3(8, 32), 512, 0, stream>>>(act, W8, 8192, 2048, 2048,
                                                nullptr, nullptr, nullptr, qb, qscale);
    // K
    transpose_f32_bf16<<<dim3(64, 64), tb, 0, stream>>>(wk, W8, 2048, 2048);
    gemm256<0><<<dim3(8, 32), 512, 0, stream>>>(act, W8, 8192, 2048, 2048,
                                                nullptr, nullptr, nullptr, kb, 1.f);
    // V
    transpose_f32_bf16<<<dim3(64, 64), tb, 0, stream>>>(wv, W8, 2048, 2048);
    gemm256<0><<<dim3(8, 32), 512, 0, stream>>>(act, W8, 8192, 2048, 2048,
                                                nullptr, nullptr, nullptr, vb, 1.f);

    // V -> V^T per (b,h)
    transpose_v_bh<<<dim3(4, 64, 64), tb, 0, stream>>>(vb, vtb);

    // attention -> act ([B,S,D] bf16)
    attn_kernel<<<dim3(32, 64), 256, 0, stream>>>(qb, kb, vtb, act);

    // O-proj + residual -> x1 (= d_out, fp32)
    transpose_f32_bf16<<<dim3(64, 64), tb, 0, stream>>>(wo, W8, 2048, 2048);
    gemm256<1><<<dim3(8, 32), 512, 0, stream>>>(act, W8, 8192, 2048, 2048,
                                                nullptr, x, x1, nullptr, 1.f);

    // LN2: x1 -> h2 (bf16, into act)
    ln_kernel<<<8192, 256, 0, stream>>>(x1, ln2w, ln2b, act);

    // FC1 + bias + gelu_new -> mid (bf16)
    transpose_f32_bf16<<<dim3(256, 64), tb, 0, stream>>>(fc1w, W32, 2048, 8192);
    gemm256<2><<<dim3(32, 32), 512, 0, stream>>>(act, W32, 8192, 8192, 2048,
                                                 fc1b, nullptr, nullptr, mid, 1.f);

    // FC2 + bias + residual(x1 in d_out) -> d_out (in-place RMW, one touch/elem)
    transpose_f32_bf16<<<dim3(64, 256), tb, 0, stream>>>(fc2w, W32, 8192, 2048);
    gemm256<3><<<dim3(8, 32), 512, 0, stream>>>(mid, W32, 8192, 2048, 8192,
                                                fc2b, x1, out, nullptr, 1.f);
}

// Round 4
// 1519.929 us; speedup vs baseline: 1.0959x; 1.0162x over previous
//
#include <hip/hip_runtime.h>
#include <cstdint>
#include <cstddef>

// ---------------------------------------------------------------------------
// EncoderBlock: pre-norm MHA + pre-norm MLP, B=4 S=2048 D=2048 H=16 HD=128 DFF=8192
// GEMMs (R4, frozen): 256x256 tile, BK=32, 8 waves, 3-stage circular LDS
// pipeline, counted s_waitcnt vmcnt(4), raw barriers, setprio.
// Attention (R5): double-buffered K/V LDS + counted vmcnt(8) (never 0 in the
// main loop), raw s_barrier + bare asm waits (no memory clobbers -- R3 lesson:
// clobbers make LLVM insert full drains), setprio around MFMA clusters,
// grid swapped to (bh, qt) so all qt-blocks of one head land on one XCD
// (linear id = qt*64+bh, 64 == 0 mod 8) for K/V L2 locality.
// R6 = R5 resubmitted verbatim: R5 bench was an infra failure (container
// acquisition), no counters returned; kernel audit found no hang path.
// ---------------------------------------------------------------------------

typedef __attribute__((ext_vector_type(8))) __bf16 bf16x8;
typedef __attribute__((ext_vector_type(4))) float f32x4;

#define MFMA16(a, b, c) __builtin_amdgcn_mfma_f32_16x16x32_bf16((a), (b), (c), 0, 0, 0)
#define SCHED_FENCE() __builtin_amdgcn_sched_barrier(0)

__device__ __forceinline__ unsigned short f2bf(float f) {
    unsigned int u = __builtin_bit_cast(unsigned int, f);
    u = (u + 0x7FFFu + ((u >> 16) & 1u)) >> 16;   // RNE
    return (unsigned short)u;
}

__device__ __forceinline__ void async16(const void* gptr, void* lptr) {
    __builtin_amdgcn_global_load_lds(
        (const __attribute__((address_space(1))) void*)gptr,
        (__attribute__((address_space(3))) void*)lptr, 16, 0, 0);
}

// ---------------------------------------------------------------------------
// Weight transpose + fp32->bf16 cast:  W[K][N] fp32  ->  WT[N][K] bf16
// ---------------------------------------------------------------------------
__global__ void transpose_f32_bf16(const float* __restrict__ W,
                                   unsigned short* __restrict__ WT, int K, int N) {
    __shared__ float t[32][33];
    const int n0 = blockIdx.x * 32, k0 = blockIdx.y * 32;
    const int tx = threadIdx.x, ty = threadIdx.y;
#pragma unroll
    for (int i = 0; i < 4; ++i)
        t[ty + i * 8][tx] = W[(size_t)(k0 + ty + i * 8) * N + n0 + tx];
    __syncthreads();
#pragma unroll
    for (int i = 0; i < 4; ++i)
        WT[(size_t)(n0 + ty + i * 8) * K + k0 + tx] = f2bf(t[tx][ty + i * 8]);
}

// per-(b,h) bf16 transpose: V [BH][2048][128] -> VT [BH][128][2048]
__global__ void transpose_v_bh(const unsigned short* __restrict__ V,
                               unsigned short* __restrict__ VT) {
    __shared__ unsigned short t[32][33];
    const int bh = blockIdx.z;
    const unsigned short* src = V + (size_t)bh * 2048 * 128;
    unsigned short* dst = VT + (size_t)bh * 128 * 2048;
    const int n0 = blockIdx.x * 32;   // hd
    const int k0 = blockIdx.y * 32;   // s
    const int tx = threadIdx.x, ty = threadIdx.y;
#pragma unroll
    for (int i = 0; i < 4; ++i)
        t[ty + i * 8][tx] = src[(size_t)(k0 + ty + i * 8) * 128 + n0 + tx];
    __syncthreads();
#pragma unroll
    for (int i = 0; i < 4; ++i)
        dst[(size_t)(n0 + ty + i * 8) * 2048 + k0 + tx] = t[tx][ty + i * 8];
}

// ---------------------------------------------------------------------------
// LayerNorm over D=2048, one 256-thread block per row, fp32 in -> bf16 out
// ---------------------------------------------------------------------------
__global__ void __launch_bounds__(256)
ln_kernel(const float* __restrict__ x, const float* __restrict__ w,
          const float* __restrict__ b, unsigned short* __restrict__ out) {
    const int row = blockIdx.x;
    const int tid = threadIdx.x;
    const float* xr = x + (size_t)row * 2048;
    float4 v0 = *reinterpret_cast<const float4*>(xr + tid * 8);
    float4 v1 = *reinterpret_cast<const float4*>(xr + tid * 8 + 4);
    float vv[8] = {v0.x, v0.y, v0.z, v0.w, v1.x, v1.y, v1.z, v1.w};
    float s = 0.f, q = 0.f;
#pragma unroll
    for (int j = 0; j < 8; ++j) { s += vv[j]; q += vv[j] * vv[j]; }
#pragma unroll
    for (int off = 32; off >= 1; off >>= 1) {
        s += __shfl_down(s, off);
        q += __shfl_down(q, off);
    }
    __shared__ float red[8];
    const int lane = tid & 63, wv = tid >> 6;
    if (lane == 0) { red[wv] = s; red[4 + wv] = q; }
    __syncthreads();
    s = red[0] + red[1] + red[2] + red[3];
    q = red[4] + red[5] + red[6] + red[7];
    const float mu = s * (1.f / 2048.f);
    const float var = q * (1.f / 2048.f) - mu * mu;
    const float rstd = rsqrtf(var + 1e-5f);
    alignas(16) unsigned short pk[8];
    const float* wp = w + tid * 8;
    const float* bp = b + tid * 8;
#pragma unroll
    for (int j = 0; j < 8; ++j)
        pk[j] = f2bf((vv[j] - mu) * rstd * wp[j] + bp[j]);
    *reinterpret_cast<uint4*>(out + (size_t)row * 2048 + tid * 8) =
        *reinterpret_cast<const uint4*>(pk);
}

// ---------------------------------------------------------------------------
// GEMM: C[M,N] = A[M,K] @ BT[N,K]^T   (A,BT bf16 row-major)  -- FROZEN (R4)
// 256x256 tile, BK=32, 512 threads = 8 waves (2 wave-rows x 4 wave-cols),
// per-wave 128x64 output (acc[8][4] of 16x16 frags), 16x16x32 MFMA.
// 3-stage circular LDS buffers, counted s_waitcnt vmcnt(4) at tile boundary.
// Epilogues: 0 = bf16 head-layout [B,H,S,HD] with scale (QKV)
//            1 = fp32 resid + acc                         (O-proj)
//            2 = bf16 gelu_new(acc + bias)                (FC1)
//            3 = fp32 acc + bias + resid (in-place ok)    (FC2)
// ---------------------------------------------------------------------------
template <int EPI>
__global__ void __launch_bounds__(512, 2)
gemm256(const unsigned short* __restrict__ A, const unsigned short* __restrict__ BT,
        int M, int N, int K,
        const float* __restrict__ bias, const float* __restrict__ resid,
        float* __restrict__ outF, unsigned short* __restrict__ outB, float scale) {
    __shared__ __align__(16) unsigned short lds[6 * 8192];  // 96 KiB: A x3, B x3
    unsigned short* const sA = lds;
    unsigned short* const sB = lds + 3 * 8192;
    const int tid = threadIdx.x;
    const int lane = tid & 63;
    const int w = tid >> 6;
    const int wr = w >> 2;     // 0..1  (wave row: 128 C-rows each)
    const int wc = w & 3;      // 0..3  (wave col: 64 C-cols each)
    const int g = lane >> 4, lr = lane & 15;
    const int m0 = blockIdx.y * 256, n0 = blockIdx.x * 256;

    const int r0 = tid >> 2;
    const int c0 = (((tid & 3) - (r0 >> 1)) & 3) * 8;
    const unsigned short* gA0 = A + (size_t)(m0 + r0) * K + c0;
    const unsigned short* gA1 = A + (size_t)(m0 + r0 + 128) * K + c0;
    const unsigned short* gB0 = BT + (size_t)(n0 + r0) * K + c0;
    const unsigned short* gB1 = BT + (size_t)(n0 + r0 + 128) * K + c0;

    const int sslot = ((g + ((lr >> 1) & 3)) & 3) * 8;   // in ushorts

    f32x4 acc[8][4];
#pragma unroll
    for (int i = 0; i < 8; ++i)
#pragma unroll
        for (int j = 0; j < 4; ++j)
            acc[i][j] = (f32x4){0.f, 0.f, 0.f, 0.f};

    const int NT = K >> 5;

    // prologue: tile0 -> buf0 (oldest 4 loads), tile1 -> buf1
    async16(gA0, &sA[tid * 8]);
    async16(gA1, &sA[(tid + 512) * 8]);
    async16(gB0, &sB[tid * 8]);
    async16(gB1, &sB[(tid + 512) * 8]);
    async16(gA0 + 32, &sA[8192 + tid * 8]);
    async16(gA1 + 32, &sA[8192 + (tid + 512) * 8]);
    async16(gB0 + 32, &sB[8192 + tid * 8]);
    async16(gB1 + 32, &sB[8192 + (tid + 512) * 8]);
    asm volatile("s_waitcnt vmcnt(4)");   // tile0 landed (bare: no mem clobber!)
    SCHED_FENCE();
    __builtin_amdgcn_s_barrier();
    SCHED_FENCE();

    int bc = 0;
    for (int t = 0; t < NT; ++t) {
        const unsigned short* aC = sA + bc * 8192;
        const unsigned short* bC = sB + bc * 8192;
        int bs = bc + 2; if (bs >= 3) bs -= 3;
        unsigned short* aS = sA + bs * 8192;
        unsigned short* bS = sB + bs * 8192;
        const bool pf = (t + 2 < NT);
        const int kpf = (t + 2) * 32;

        bf16x8 af[4], bfr[4];
        // ---- phase 0: mb 0..3 x nb 0..3 ----
#pragma unroll
        for (int i = 0; i < 4; ++i)
            af[i] = *reinterpret_cast<const bf16x8*>(
                &aC[(wr * 128 + i * 16 + lr) * 32 + sslot]);
#pragma unroll
        for (int nf = 0; nf < 4; ++nf)
            bfr[nf] = *reinterpret_cast<const bf16x8*>(
                &bC[(wc * 64 + nf * 16 + lr) * 32 + sslot]);
        if (pf) {
            async16(gA0 + kpf, &aS[tid * 8]);
            async16(gA1 + kpf, &aS[(tid + 512) * 8]);
        }
        SCHED_FENCE();
        __builtin_amdgcn_s_barrier();
        SCHED_FENCE();
        __builtin_amdgcn_s_setprio(1);
#pragma unroll
        for (int mb = 0; mb < 4; ++mb)
#pragma unroll
            for (int nb = 0; nb < 4; ++nb)
                acc[mb][nb] = MFMA16(af[mb], bfr[nb], acc[mb][nb]);
        __builtin_amdgcn_s_setprio(0);
        SCHED_FENCE();
        __builtin_amdgcn_s_barrier();
        SCHED_FENCE();
        // ---- phase 1: mb 4..7 x nb 0..3 (bfr reused) ----
#pragma unroll
        for (int i = 0; i < 4; ++i)
            af[i] = *reinterpret_cast<const bf16x8*>(
                &aC[(wr * 128 + 64 + i * 16 + lr) * 32 + sslot]);
        if (pf) {
            async16(gB0 + kpf, &bS[tid * 8]);
            async16(gB1 + kpf, &bS[(tid + 512) * 8]);
        }
        SCHED_FENCE();
        __builtin_amdgcn_s_barrier();
        SCHED_FENCE();
        __builtin_amdgcn_s_setprio(1);
#pragma unroll
        for (int mb = 0; mb < 4; ++mb)
#pragma unroll
            for (int nb = 0; nb < 4; ++nb)
                acc[4 + mb][nb] = MFMA16(af[mb], bfr[nb], acc[4 + mb][nb]);
        __builtin_amdgcn_s_setprio(0);
        SCHED_FENCE();
        if (t < NT - 1) {
            if (pf) asm volatile("s_waitcnt vmcnt(4)");
            else    asm volatile("s_waitcnt vmcnt(0)");
        }
        SCHED_FENCE();
        __builtin_amdgcn_s_barrier();
        SCHED_FENCE();
        bc = (bc + 1 == 3) ? 0 : bc + 1;
    }

    // epilogue: C row = m0 + wr*128 + mb*16 + g*4 + r, col = n0 + wc*64 + nb*16 + lr
#pragma unroll
    for (int mb = 0; mb < 8; ++mb) {
#pragma unroll
        for (int r = 0; r < 4; ++r) {
            const int m = m0 + wr * 128 + mb * 16 + g * 4 + r;
#pragma unroll
            for (int nb = 0; nb < 4; ++nb) {
                const int n = n0 + wc * 64 + nb * 16 + lr;
                float v = acc[mb][nb][r];
                if constexpr (EPI == 0) {
                    v *= scale;
                    const int b = m >> 11, s = m & 2047;
                    const int h = n >> 7, hd = n & 127;
                    outB[(((size_t)(b * 16 + h) * 2048 + s) << 7) + hd] = f2bf(v);
                } else if constexpr (EPI == 1) {
                    const size_t idx = (size_t)m * N + n;
                    outF[idx] = resid[idx] + v;
                } else if constexpr (EPI == 2) {
                    v += bias[n];
                    const float u = 0.7978845608028654f * (v + 0.044715f * v * v * v);
                    const float ge = 0.5f * v * (1.f + tanhf(u));
                    outB[(size_t)m * N + n] = f2bf(ge);
                } else {
                    const size_t idx = (size_t)m * N + n;
                    outF[idx] = v + bias[n] + resid[idx];
                }
            }
        }
    }
}

// ---------------------------------------------------------------------------
// Flash attention (R5): 256 threads = 4 waves. Grid (bh=x, qt=y) for XCD/L2
// locality. Double-buffered K/V in LDS (72 KiB total), counted vmcnt(8):
// per tile {issue 8 loads for t+1 -> buf^1 ; s_waitcnt vmcnt(8) ; s_barrier ;
// compute from buf ; s_barrier}. Loads for t+1 stay in flight across the
// whole compute of tile t. setprio(1) around both MFMA clusters.
// Q,K in [B,H,S,HD] bf16 (Q pre-scaled), V in [B,H,HD,S] bf16. O -> [B,S,D].
// ---------------------------------------------------------------------------
__global__ void __launch_bounds__(256)
attn_kernel(const unsigned short* __restrict__ Q, const unsigned short* __restrict__ Kt,
            const unsigned short* __restrict__ VT, unsigned short* __restrict__ O) {
    __shared__ __align__(16) unsigned short lK[2][64 * 128];   // 32 KB [key][hd]
    __shared__ __align__(16) unsigned short lV[2][128 * 64];   // 32 KB [hd][key]
    __shared__ __align__(16) unsigned short lP[4][16 * 64];    //  8 KB per-wave P
    const int bh = blockIdx.x;     // swapped: id = qt*64+bh, 64%8==0 -> all qt
    const int qt = blockIdx.y;     // blocks of a head share one XCD's L2
    const int tid = threadIdx.x;
    const int w = tid >> 6;
    const int lane = tid & 63;
    const int g = lane >> 4, lr = lane & 15;
    const unsigned short* Qp = Q + ((size_t)bh * 2048 + qt * 64 + w * 16) * 128;
    const unsigned short* Kp = Kt + (size_t)bh * 2048 * 128;
    const unsigned short* Vp = VT + (size_t)bh * 128 * 2048;
    unsigned short* Pw = lP[w];

    bf16x8 qf[4];
#pragma unroll
    for (int c = 0; c < 4; ++c)
        qf[c] = *reinterpret_cast<const bf16x8*>(&Qp[lr * 128 + c * 32 + g * 8]);

    f32x4 o[8];
#pragma unroll
    for (int db = 0; db < 8; ++db) o[db] = (f32x4){0.f, 0.f, 0.f, 0.f};
    float mm[4] = {-1e30f, -1e30f, -1e30f, -1e30f};
    float ll[4] = {0.f, 0.f, 0.f, 0.f};

    int kR[4], kJ[4], vR[4], vJ[4];
#pragma unroll
    for (int c = 0; c < 4; ++c) {
        const int chunk = tid + c * 256;
        kR[c] = chunk >> 4;
        kJ[c] = ((chunk & 15) ^ (kR[c] & 15)) * 8;
        vR[c] = chunk >> 3;
        vJ[c] = ((chunk & 7) ^ (vR[c] & 7)) * 8;
    }

    // prologue: stage tile 0 into buf 0
#pragma unroll
    for (int c = 0; c < 4; ++c) {
        async16(&Kp[(size_t)kR[c] * 128 + kJ[c]], &lK[0][(size_t)(tid + c * 256) * 8]);
        async16(&Vp[(size_t)vR[c] * 2048 + vJ[c]], &lV[0][(size_t)(tid + c * 256) * 8]);
    }

    for (int kt = 0; kt < 32; ++kt) {
        const int cur = kt & 1;
        // issue next tile's loads into buf^1 (that buffer's readers all passed
        // the previous end-barrier), then counted wait: tile kt's 8 loads have
        // landed, tile kt+1's 8 remain in flight under the whole compute.
        if (kt + 1 < 32) {
            const int kb = (kt + 1) * 64;
#pragma unroll
            for (int c = 0; c < 4; ++c) {
                async16(&Kp[(size_t)(kb + kR[c]) * 128 + kJ[c]],
                        &lK[cur ^ 1][(size_t)(tid + c * 256) * 8]);
                async16(&Vp[(size_t)vR[c] * 2048 + kb + vJ[c]],
                        &lV[cur ^ 1][(size_t)(tid + c * 256) * 8]);
            }
            asm volatile("s_waitcnt vmcnt(8)");
        } else {
            asm volatile("s_waitcnt vmcnt(0)");
        }
        SCHED_FENCE();
        __builtin_amdgcn_s_barrier();
        SCHED_FENCE();

        // S = Q K^T for 4 key-blocks of 16
        f32x4 sc[4];
#pragma unroll
        for (int j16 = 0; j16 < 4; ++j16) sc[j16] = (f32x4){0.f, 0.f, 0.f, 0.f};
        __builtin_amdgcn_s_setprio(1);
#pragma unroll
        for (int j16 = 0; j16 < 4; ++j16) {
            const int krow = j16 * 16 + lr;
#pragma unroll
            for (int c = 0; c < 4; ++c) {
                bf16x8 kf = *reinterpret_cast<const bf16x8*>(
                    &lK[cur][krow * 128 + (((c * 4 + g) ^ lr) & 15) * 8]);
                sc[j16] = MFMA16(qf[c], kf, sc[j16]);
            }
        }
        __builtin_amdgcn_s_setprio(0);

        // online softmax (rows g*4+r, 16 cols per group spread over lanes of g)
        float al[4];
        float pr[4][4];
#pragma unroll
        for (int r = 0; r < 4; ++r) {
            float mx = fmaxf(fmaxf(sc[0][r], sc[1][r]), fmaxf(sc[2][r], sc[3][r]));
            mx = fmaxf(mx, __shfl_xor(mx, 1));
            mx = fmaxf(mx, __shfl_xor(mx, 2));
            mx = fmaxf(mx, __shfl_xor(mx, 4));
            mx = fmaxf(mx, __shfl_xor(mx, 8));
            const float nm = fmaxf(mm[r], mx);
            al[r] = __expf(mm[r] - nm);
            float rs = 0.f;
#pragma unroll
            for (int j16 = 0; j16 < 4; ++j16) {
                pr[j16][r] = __expf(sc[j16][r] - nm);
                rs += pr[j16][r];
            }
            rs += __shfl_xor(rs, 1);
            rs += __shfl_xor(rs, 2);
            rs += __shfl_xor(rs, 4);
            rs += __shfl_xor(rs, 8);
            ll[r] = ll[r] * al[r] + rs;
            mm[r] = nm;
        }
#pragma unroll
        for (int db = 0; db < 8; ++db) {
            o[db][0] *= al[0]; o[db][1] *= al[1];
            o[db][2] *= al[2]; o[db][3] *= al[3];
        }

        // P (C-layout) -> LDS (swizzled [row][key]) -> A-layout fragments
#pragma unroll
        for (int j16 = 0; j16 < 4; ++j16)
#pragma unroll
            for (int r = 0; r < 4; ++r) {
                const int row = g * 4 + r;
                const int ch = j16 * 2 + (lr >> 3);
                Pw[row * 64 + ((ch ^ (row & 7)) * 8) + (lr & 7)] = f2bf(pr[j16][r]);
            }
        // wave-internal LDS write->read; compiler inserts lgkmcnt wait

        // O += P V
        __builtin_amdgcn_s_setprio(1);
#pragma unroll
        for (int kk = 0; kk < 2; ++kk) {
            bf16x8 pf = *reinterpret_cast<const bf16x8*>(
                &Pw[lr * 64 + (((kk * 4 + g) ^ (lr & 7)) & 7) * 8]);
#pragma unroll
            for (int db = 0; db < 8; ++db) {
                const int vrow = db * 16 + lr;
                bf16x8 vf = *reinterpret_cast<const bf16x8*>(
                    &lV[cur][vrow * 64 + (((kk * 4 + g) ^ (vrow & 7)) & 7) * 8]);
                o[db] = MFMA16(pf, vf, o[db]);
            }
        }
        __builtin_amdgcn_s_setprio(0);
        SCHED_FENCE();
        __builtin_amdgcn_s_barrier();   // buf[cur] free for tile kt+2's loads
        SCHED_FENCE();
    }

    const int b = bh >> 4, h = bh & 15;
#pragma unroll
    for (int db = 0; db < 8; ++db)
#pragma unroll
        for (int r = 0; r < 4; ++r) {
            const int s = qt * 64 + w * 16 + g * 4 + r;
            const float v = o[db][r] / ll[r];
            O[((size_t)(b * 2048 + s)) * 2048 + h * 128 + db * 16 + lr] = f2bf(v);
        }
}

// ---------------------------------------------------------------------------
extern "C" void kernel_launch(void* const* d_in, const int* in_sizes, int n_in,
                              void* d_out, int out_size, void* d_ws, size_t ws_size,
                              hipStream_t stream) {
    const float* x    = (const float*)d_in[0];
    const float* wq   = (const float*)d_in[1];
    const float* wk   = (const float*)d_in[2];
    const float* wv   = (const float*)d_in[3];
    const float* wo   = (const float*)d_in[4];
    const float* ln1w = (const float*)d_in[5];
    const float* ln1b = (const float*)d_in[6];
    const float* ln2w = (const float*)d_in[7];
    const float* ln2b = (const float*)d_in[8];
    const float* fc1w = (const float*)d_in[9];
    const float* fc1b = (const float*)d_in[10];
    const float* fc2w = (const float*)d_in[11];
    const float* fc2b = (const float*)d_in[12];
    float* out = (float*)d_out;

    const size_t MB = 1024ull * 1024ull;
    if (ws_size < 200 * MB) return;  // diagnostic guard

    char* ws = (char*)d_ws;
    unsigned short* W8   = (unsigned short*)(ws + 0 * MB);    //  8 MB: wqT/wkT/wvT/woT (seq.)
    unsigned short* W32  = (unsigned short*)(ws + 8 * MB);    // 32 MB: fc1T then fc2T
    unsigned short* act  = (unsigned short*)(ws + 40 * MB);   // 32 MB: h -> attnO -> h2
    unsigned short* qb   = (unsigned short*)(ws + 72 * MB);   // 32 MB
    unsigned short* kb   = (unsigned short*)(ws + 104 * MB);  // 32 MB
    unsigned short* vb   = (unsigned short*)(ws + 136 * MB);  // 32 MB
    unsigned short* vtb  = (unsigned short*)(ws + 168 * MB);  // 32 MB
    unsigned short* mid  = qb;                                // 128 MB overlay (post-attn)
    float*          x1   = out;                               // x + attn proj in d_out

    const dim3 tb(32, 8);
    const float qscale = 0.08838834764831845f;

    // LN1: x -> h (bf16)
    ln_kernel<<<8192, 256, 0, stream>>>(x, ln1w, ln1b, act);

    // Q = h @ wq (scaled), head layout
    transpose_f32_bf16<<<dim3(64, 64), tb, 0, stream>>>(wq, W8, 2048, 2048);
    gemm256<0><<<dim3(8, 32), 512, 0, stream>>>(act, W8, 8192, 2048, 2048,
                                                nullptr, nullptr, nullptr, qb, qscale);
    // K
    transpose_f32_bf16<<<dim3(64, 64), tb, 0, stream>>>(wk, W8, 2048, 2048);
    gemm256<0><<<dim3(8, 32), 512, 0, stream>>>(act, W8, 8192, 2048, 2048,
                                                nullptr, nullptr, nullptr, kb, 1.f);
    // V
    transpose_f32_bf16<<<dim3(64, 64), tb, 0, stream>>>(wv, W8, 2048, 2048);
    gemm256<0><<<dim3(8, 32), 512, 0, stream>>>(act, W8, 8192, 2048, 2048,
                                                nullptr, nullptr, nullptr, vb, 1.f);

    // V -> V^T per (b,h)
    transpose_v_bh<<<dim3(4, 64, 64), tb, 0, stream>>>(vb, vtb);

    // attention -> act ([B,S,D] bf16); grid = (bh, qt) for XCD locality
    attn_kernel<<<dim3(64, 32), 256, 0, stream>>>(qb, kb, vtb, act);

    // O-proj + residual -> x1 (= d_out, fp32)
    transpose_f32_bf16<<<dim3(64, 64), tb, 0, stream>>>(wo, W8, 2048, 2048);
    gemm256<1><<<dim3(8, 32), 512, 0, stream>>>(act, W8, 8192, 2048, 2048,
                                                nullptr, x, x1, nullptr, 1.f);

    // LN2: x1 -> h2 (bf16, into act)
    ln_kernel<<<8192, 256, 0, stream>>>(x1, ln2w, ln2b, act);

    // FC1 + bias + gelu_new -> mid (bf16)
    transpose_f32_bf16<<<dim3(256, 64), tb, 0, stream>>>(fc1w, W32, 2048, 8192);
    gemm256<2><<<dim3(32, 32), 512, 0, stream>>>(act, W32, 8192, 8192, 2048,
                                                 fc1b, nullptr, nullptr, mid, 1.f);

    // FC2 + bias + residual(x1 in d_out) -> d_out (in-place RMW, one touch/elem)
    transpose_f32_bf16<<<dim3(64, 256), tb, 0, stream>>>(fc2w, W32, 8192, 2048);
    gemm256<3><<<dim3(8, 32), 512, 0, stream>>>(mid, W32, 8192, 2048, 8192,
                                                fc2b, x1, out, nullptr, 1.f);
}